// Round 4
// baseline (227.464 us; speedup 1.0000x reference)
//
#include <hip/hip_runtime.h>
#include <hip/hip_bf16.h>

// TensorProductConv, round 4: R2 structure (bucket-by-row + one wave per row)
// + register-preloaded bucket with CONVERGED shfl broadcast (R3's divergent
// shfl bug fixed: loop trip count is wave-uniform, shfls issue before the
// predicated body), unroll-by-2, nontemporal W loads / Z stores.
//
// X: (V, 4*C) f32, Y: (E, 4) f32, W: (E, 5*C) f32, rows/cols: (E,) int32.
// Z: (V, 11*C) f32.  C = 32, V = 50000, E = 800000 (avg degree 16).

#define C 32
#define ZCOLS (11 * C)
#define MAXDEG 64          // Poisson(16): P(deg > 64) ~ 1e-18 per row; overflow list backs this up
#define OVF_MAX 65536
#define INV_SQRT3 0.57735026918962576451f
#define INV_SQRT2 0.70710678118654752440f

// ---------------- phase 1: bucket edges by destination row ----------------
__global__ void hist_scatter(const int* __restrict__ rows,
                             int* __restrict__ cnt,
                             int* __restrict__ bucket,
                             int* __restrict__ ovf_cnt,
                             int* __restrict__ ovf_list,
                             int E) {
    int e = blockIdx.x * blockDim.x + threadIdx.x;
    if (e >= E) return;
    int r = rows[e];
    int k = atomicAdd(&cnt[r], 1);
    if (k < MAXDEG) {
        bucket[(size_t)r * MAXDEG + k] = e;
    } else {
        int o = atomicAdd(ovf_cnt, 1);
        if (o < OVF_MAX) ovf_list[o] = e;
    }
}

// ---------------- phase 2: one wave per row, register accumulation ----------------
__global__ void tpconv_rows(const float* __restrict__ X,
                            const float* __restrict__ Y,
                            const float* __restrict__ W,
                            const int* __restrict__ cols,
                            const int* __restrict__ cnt,
                            const int* __restrict__ bucket,
                            float* __restrict__ Z,
                            int V) {
    int wid  = blockIdx.x * (blockDim.x >> 6) + (threadIdx.x >> 6);
    int lane = threadIdx.x & 63;
    if (wid >= V) return;
    const int c = lane & 31;   // channel owned by this lane
    const int h = lane >> 5;   // half-wave: h=0 takes even edges, h=1 odd edges

    int n = cnt[wid];          // wave-uniform
    if (n > MAXDEG) n = MAXDEG;

    // preload the whole bucket list (<=64 entries) into one register/lane
    const int* bkt = bucket + (size_t)wid * MAXDEG;
    int ebkt = (lane < n) ? bkt[lane] : 0;

    float acc[11];
#pragma unroll
    for (int j = 0; j < 11; ++j) acc[j] = 0.0f;

    auto body = [&](int e) {
        const float4 y = *reinterpret_cast<const float4*>(Y + (size_t)e * 4);
        const int col = cols[e];

        const float* Xe = X + (size_t)col * (4 * C);
        const float xj0 = Xe[c];
        const float a0  = Xe[C + 3 * c + 0];
        const float a1  = Xe[C + 3 * c + 1];
        const float a2  = Xe[C + 3 * c + 2];

        // W row is touched by exactly one wave, once: keep it out of L2.
        const float* We = W + (size_t)e * (5 * C);
        const float w0 = __builtin_nontemporal_load(We + 0 * C + c);
        const float w1 = __builtin_nontemporal_load(We + 1 * C + c);
        const float w2 = __builtin_nontemporal_load(We + 2 * C + c);
        const float w3 = __builtin_nontemporal_load(We + 3 * C + c);
        const float w4 = __builtin_nontemporal_load(We + 4 * C + c);

        acc[0] += w0 * xj0 * y.x;

        const float t01 = w1 * xj0;
        acc[1] += t01 * y.y;
        acc[2] += t01 * y.z;
        acc[3] += t01 * y.w;

        const float t10 = w2 * y.x;
        acc[4] += t10 * a0;
        acc[5] += t10 * a1;
        acc[6] += t10 * a2;

        acc[7] += w3 * (a0 * y.y + a1 * y.z + a2 * y.w) * INV_SQRT3;

        const float s = w4 * INV_SQRT2;
        acc[8]  += s * (a1 * y.w - a2 * y.z);
        acc[9]  += s * (a2 * y.y - a0 * y.w);
        acc[10] += s * (a0 * y.z - a1 * y.y);
    };

    // Wave-uniform trip count; all shfls issue while the wave is CONVERGED.
    // Half-wave h handles odd/even indices h, h+2, ...; unroll-by-2 gives
    // indices 4j+h and 4j+2+h per iteration. Max index 4*jmax-1 <= 63.
    const int jmax = (n + 3) >> 2;
    for (int j = 0; j < jmax; ++j) {
        const int ia = 4 * j + h;
        const int ib = 4 * j + 2 + h;
        const int ea = __shfl(ebkt, ia);
        const int eb = __shfl(ebkt, ib);
        if (ia < n) body(ea);
        if (ib < n) body(eb);
    }

    // combine the two half-wave partial sums (converged here)
#pragma unroll
    for (int j = 0; j < 11; ++j) acc[j] += __shfl_xor(acc[j], 32);

    if (h == 0) {
        // Z is write-once: nontemporal stores keep it from displacing L2.
        float* Zr = Z + (size_t)wid * ZCOLS;
        __builtin_nontemporal_store(acc[0],  Zr + c);
        __builtin_nontemporal_store(acc[1],  Zr + C + 3 * c + 0);
        __builtin_nontemporal_store(acc[2],  Zr + C + 3 * c + 1);
        __builtin_nontemporal_store(acc[3],  Zr + C + 3 * c + 2);
        __builtin_nontemporal_store(acc[4],  Zr + 4 * C + 3 * c + 0);
        __builtin_nontemporal_store(acc[5],  Zr + 4 * C + 3 * c + 1);
        __builtin_nontemporal_store(acc[6],  Zr + 4 * C + 3 * c + 2);
        __builtin_nontemporal_store(acc[7],  Zr + 7 * C + c);
        __builtin_nontemporal_store(acc[8],  Zr + 8 * C + 3 * c + 0);
        __builtin_nontemporal_store(acc[9],  Zr + 8 * C + 3 * c + 1);
        __builtin_nontemporal_store(acc[10], Zr + 8 * C + 3 * c + 2);
    }
}

// ---------------- phase 3: rare-overflow fallback (normally 0 edges) ----------------
__global__ void ovf_apply(const float* __restrict__ X,
                          const float* __restrict__ Y,
                          const float* __restrict__ W,
                          const int* __restrict__ rows,
                          const int* __restrict__ cols,
                          const int* __restrict__ ovf_cnt,
                          const int* __restrict__ ovf_list,
                          float* __restrict__ Z) {
    int no = *ovf_cnt;
    if (no > OVF_MAX) no = OVF_MAX;
    int total = no * C;
    for (int t = blockIdx.x * blockDim.x + threadIdx.x; t < total;
         t += gridDim.x * blockDim.x) {
        const int i = t >> 5, c = t & 31;
        const int e = ovf_list[i];
        const float4 y = *reinterpret_cast<const float4*>(Y + (size_t)e * 4);
        const int row = rows[e];
        const int col = cols[e];
        const float* Xe = X + (size_t)col * (4 * C);
        const float xj0 = Xe[c];
        const float a0  = Xe[C + 3 * c + 0];
        const float a1  = Xe[C + 3 * c + 1];
        const float a2  = Xe[C + 3 * c + 2];
        const float* We = W + (size_t)e * (5 * C);
        const float w0 = We[c], w1 = We[C + c], w2 = We[2 * C + c],
                    w3 = We[3 * C + c], w4 = We[4 * C + c];
        float* Zr = Z + (size_t)row * ZCOLS;
        atomicAdd(&Zr[c], w0 * xj0 * y.x);
        const float t01 = w1 * xj0;
        atomicAdd(&Zr[C + 3 * c + 0], t01 * y.y);
        atomicAdd(&Zr[C + 3 * c + 1], t01 * y.z);
        atomicAdd(&Zr[C + 3 * c + 2], t01 * y.w);
        const float t10 = w2 * y.x;
        atomicAdd(&Zr[4 * C + 3 * c + 0], t10 * a0);
        atomicAdd(&Zr[4 * C + 3 * c + 1], t10 * a1);
        atomicAdd(&Zr[4 * C + 3 * c + 2], t10 * a2);
        atomicAdd(&Zr[7 * C + c], w3 * (a0 * y.y + a1 * y.z + a2 * y.w) * INV_SQRT3);
        const float s = w4 * INV_SQRT2;
        atomicAdd(&Zr[8 * C + 3 * c + 0], s * (a1 * y.w - a2 * y.z));
        atomicAdd(&Zr[8 * C + 3 * c + 1], s * (a2 * y.y - a0 * y.w));
        atomicAdd(&Zr[8 * C + 3 * c + 2], s * (a0 * y.z - a1 * y.y));
    }
}

extern "C" void kernel_launch(void* const* d_in, const int* in_sizes, int n_in,
                              void* d_out, int out_size, void* d_ws, size_t ws_size,
                              hipStream_t stream) {
    const float* X    = (const float*)d_in[0];
    const float* Y    = (const float*)d_in[1];
    const float* W    = (const float*)d_in[2];
    const int*   rows = (const int*)d_in[3];
    const int*   cols = (const int*)d_in[4];
    float*       Z    = (float*)d_out;

    const int E = in_sizes[1] / 4;        // Y is (E, 4)
    const int V = in_sizes[0] / (4 * C);  // X is (V, 4*C)

    // workspace layout: [cnt: V][ovf_cnt: 1][ovf_list: OVF_MAX][bucket: V*MAXDEG]
    int* cnt      = (int*)d_ws;
    int* ovf_cnt  = cnt + V;
    int* ovf_list = ovf_cnt + 1;
    int* bucket   = ovf_list + OVF_MAX;

    // zero counters (cnt + ovf_cnt contiguous)
    hipMemsetAsync(cnt, 0, (size_t)(V + 1) * sizeof(int), stream);

    {
        const int threads = 256;
        const int blocks = (E + threads - 1) / threads;
        hist_scatter<<<blocks, threads, 0, stream>>>(rows, cnt, bucket, ovf_cnt,
                                                     ovf_list, E);
    }
    {
        const int threads = 256;                  // 4 waves/block
        const int wavesPerBlock = threads / 64;
        const int blocks = (V + wavesPerBlock - 1) / wavesPerBlock;
        tpconv_rows<<<blocks, threads, 0, stream>>>(X, Y, W, cols, cnt, bucket, Z, V);
    }
    {
        ovf_apply<<<64, 256, 0, stream>>>(X, Y, W, rows, cols, ovf_cnt, ovf_list, Z);
    }
}